// Round 2
// baseline (23.231 us; speedup 1.0000x reference)
//
#include <hip/hip_runtime.h>

// Problem constants (fixed by the reference).
#define BB   32
#define HH   512
#define WW   512
#define HCC  256
#define WCC  256
#define NPIX (HH * WW)          // 262144 = 2^18
#define NELEM (BB * NPIX)       // 8388608 floats per output tensor

typedef float f4 __attribute__((ext_vector_type(4)));

// Output layout: d_out[0 .. NELEM)        = y_initial (copy)
//                d_out[NELEM .. 2*NELEM)  = pasted nearest-resize
__global__ __launch_bounds__(256) void TransformedSegmentation_84971632984244_kernel(
    const float* __restrict__ y_initial,
    const float* __restrict__ y_cropped,
    const int*   __restrict__ bboxes,
    float*       __restrict__ out)
{
    const int total4 = (2 * NELEM) / 4;                 // float4 work items
    const int stride = gridDim.x * blockDim.x;
    for (int i = blockIdx.x * blockDim.x + threadIdx.x; i < total4; i += stride) {
        const int e = i * 4;                            // element index (multiple of 4)
        if (e < NELEM) {
            // ---- output 0: straight streaming copy of y_initial ----
            f4 v = __builtin_nontemporal_load(reinterpret_cast<const f4*>(y_initial + e));
            __builtin_nontemporal_store(v, reinterpret_cast<f4*>(out + e));
        } else {
            // ---- output 1: nearest paste into bbox on zero canvas ----
            const int e2 = e - NELEM;
            // A wave covers 256 consecutive elements; batch stride is 2^18 and
            // row stride is 2^9, so b and r are wave-uniform.
            const int b  = __builtin_amdgcn_readfirstlane(e2 >> 18);
            const int r  = (e2 >> 9) & (HH - 1);
            const int c0 = e2 & (WW - 1);

            const int x1 = bboxes[b * 4 + 0];
            const int y1 = bboxes[b * 4 + 1];
            const int x2 = bboxes[b * 4 + 2];
            const int y2 = bboxes[b * 4 + 3];

            f4 o = {0.f, 0.f, 0.f, 0.f};
            if (r >= y1 && r < y2) {                    // wave-uniform branch
                const unsigned h = (unsigned)(y2 - y1); // in [128, 256]
                const unsigned w = (unsigned)(x2 - x1); // in [128, 256]
                // Exact magic division: for d in [128,256], M = floor(2^32/d)+1
                // (== 0xFFFFFFFF/d + 1 for all these d). For n <= 65280,
                // umulhi(n, M) == floor(n/d) exactly (n*e <= 2^24 < 2^32).
                const unsigned mh = 0xFFFFFFFFu / h + 1u;
                const unsigned mw = 0xFFFFFFFFu / w + 1u;
                const unsigned sr = __umulhi((unsigned)(r - y1) * (unsigned)HCC, mh); // in [0,255]
                const float* src = y_cropped + (((long)b * HCC + sr) << 8);
#pragma unroll
                for (int j = 0; j < 4; ++j) {
                    const int c = c0 + j;
                    float v = 0.f;
                    if (c >= x1 && c < x2) {
                        const unsigned sc = __umulhi((unsigned)(c - x1) * (unsigned)WCC, mw); // in [0,255]
                        v = src[sc];
                    }
                    o[j] = v;
                }
            }
            __builtin_nontemporal_store(o, reinterpret_cast<f4*>(out + e));
        }
    }
}

extern "C" void kernel_launch(void* const* d_in, const int* in_sizes, int n_in,
                              void* d_out, int out_size, void* d_ws, size_t ws_size,
                              hipStream_t stream) {
    // Inputs (setup_inputs order): x [unused], y_initial, y_cropped, bboxes
    const float* y_initial = (const float*)d_in[1];
    const float* y_cropped = (const float*)d_in[2];
    const int*   bboxes    = (const int*)d_in[3];
    float*       out       = (float*)d_out;

    const int total4 = (2 * NELEM) / 4;       // 4,194,304 work items
    const int block  = 256;
    int grid = (total4 + block - 1) / block;  // 16384
    if (grid > 4096) grid = 4096;             // grid-stride, 16 wg/CU

    TransformedSegmentation_84971632984244_kernel<<<grid, block, 0, stream>>>(
        y_initial, y_cropped, bboxes, out);
}

// Round 3
// 20.306 us; speedup vs baseline: 1.1441x; 1.1441x over previous
//
#include <hip/hip_runtime.h>

// Problem constants (fixed by the reference).
#define BB   32
#define HH   512
#define WW   512
#define HCC  256
#define WCC  256
#define NPIX (HH * WW)          // 262144 = 2^18
#define NELEM (BB * NPIX)       // 8388608 floats per output tensor

typedef float f4 __attribute__((ext_vector_type(4)));

// Output layout: d_out[0 .. NELEM)        = y_initial (copy)
//                d_out[NELEM .. 2*NELEM)  = pasted nearest-resize
__global__ __launch_bounds__(256) void TransformedSegmentation_84971632984244_kernel(
    const float* __restrict__ y_initial,
    const float* __restrict__ y_cropped,
    const int*   __restrict__ bboxes,
    float*       __restrict__ out)
{
    const int total4 = (2 * NELEM) / 4;                 // float4 work items
    const int stride = gridDim.x * blockDim.x;
    for (int i = blockIdx.x * blockDim.x + threadIdx.x; i < total4; i += stride) {
        const int e = i * 4;                            // element index (multiple of 4)
        if (e < NELEM) {
            // ---- output 0: straight streaming copy of y_initial ----
            const f4 v = *reinterpret_cast<const f4*>(y_initial + e);
            *reinterpret_cast<f4*>(out + e) = v;
        } else {
            // ---- output 1: nearest paste into bbox on zero canvas ----
            const int e2 = e - NELEM;
            // A wave covers 256 consecutive elements; batch stride is 2^18 and
            // row stride is 2^9, so b and r are wave-uniform.
            const int b  = __builtin_amdgcn_readfirstlane(e2 >> 18);
            const int r  = (e2 >> 9) & (HH - 1);
            const int c0 = e2 & (WW - 1);

            const int x1 = bboxes[b * 4 + 0];
            const int y1 = bboxes[b * 4 + 1];
            const int x2 = bboxes[b * 4 + 2];
            const int y2 = bboxes[b * 4 + 3];

            f4 o = {0.f, 0.f, 0.f, 0.f};
            if (r >= y1 && r < y2) {                    // wave-uniform branch
                const unsigned h = (unsigned)(y2 - y1); // in [128, 256]
                const unsigned w = (unsigned)(x2 - x1); // in [128, 256]
                // Exact magic division: for d in [128,256], M = floor(2^32/d)+1
                // (== 0xFFFFFFFF/d + 1 for all these d). For n <= 65280,
                // umulhi(n, M) == floor(n/d) exactly (n*e <= 2^24 < 2^32).
                const unsigned mh = 0xFFFFFFFFu / h + 1u;
                const unsigned mw = 0xFFFFFFFFu / w + 1u;
                const unsigned sr = __umulhi((unsigned)(r - y1) * (unsigned)HCC, mh); // in [0,255]
                const float* src = y_cropped + (((long)b * HCC + sr) << 8);
#pragma unroll
                for (int j = 0; j < 4; ++j) {
                    const int c = c0 + j;
                    float v = 0.f;
                    if (c >= x1 && c < x2) {
                        const unsigned sc = __umulhi((unsigned)(c - x1) * (unsigned)WCC, mw); // in [0,255]
                        v = src[sc];
                    }
                    o[j] = v;
                }
            }
            *reinterpret_cast<f4*>(out + e) = o;
        }
    }
}

extern "C" void kernel_launch(void* const* d_in, const int* in_sizes, int n_in,
                              void* d_out, int out_size, void* d_ws, size_t ws_size,
                              hipStream_t stream) {
    // Inputs (setup_inputs order): x [unused], y_initial, y_cropped, bboxes
    const float* y_initial = (const float*)d_in[1];
    const float* y_cropped = (const float*)d_in[2];
    const int*   bboxes    = (const int*)d_in[3];
    float*       out       = (float*)d_out;

    const int total4 = (2 * NELEM) / 4;       // 4,194,304 work items
    const int block  = 256;
    int grid = (total4 + block - 1) / block;  // 16384
    if (grid > 4096) grid = 4096;             // grid-stride, 16 wg/CU

    TransformedSegmentation_84971632984244_kernel<<<grid, block, 0, stream>>>(
        y_initial, y_cropped, bboxes, out);
}

// Round 4
// 20.182 us; speedup vs baseline: 1.1511x; 1.0061x over previous
//
#include <hip/hip_runtime.h>

// Problem constants (fixed by the reference).
#define BB   32
#define HH   512
#define WW   512
#define HCC  256
#define WCC  256
#define NPIX (HH * WW)          // 262144 = 2^18
#define NELEM (BB * NPIX)       // 8388608 floats per output tensor

typedef float f4 __attribute__((ext_vector_type(4)));

// One thread = one float4 of output0 (copy) + one float4 of output1 (paste).
// Copy load issued first so its HBM latency overlaps the paste math/gathers.
__global__ __launch_bounds__(256) void TransformedSegmentation_84971632984244_kernel(
    const float* __restrict__ y_initial,
    const float* __restrict__ y_cropped,
    const int*   __restrict__ bboxes,
    float*       __restrict__ out)
{
    const int t = blockIdx.x * blockDim.x + threadIdx.x;   // 0 .. NELEM/4
    const int e = t << 2;                                  // element index

    // ---- output 0: issue streaming copy load early ----
    const f4 v = *reinterpret_cast<const f4*>(y_initial + e);

    // ---- output 1: nearest paste into bbox on zero canvas ----
    // A wave covers 256 consecutive elements; batch stride 2^18, row stride
    // 2^9 -> b and r are wave-uniform.
    const int b  = __builtin_amdgcn_readfirstlane(e >> 18);
    const int r  = (e >> 9) & (HH - 1);
    const int c0 = e & (WW - 1);

    const int x1 = bboxes[b * 4 + 0];
    const int y1 = bboxes[b * 4 + 1];
    const int x2 = bboxes[b * 4 + 2];
    const int y2 = bboxes[b * 4 + 3];

    f4 o = {0.f, 0.f, 0.f, 0.f};
    if (r >= y1 && r < y2) {                    // wave-uniform (scalar) branch
        const unsigned h = (unsigned)(y2 - y1); // in [128, 256]
        const unsigned w = (unsigned)(x2 - x1); // in [128, 256]
        // Exact magic division: for d in [128,256], M = floor(2^32/d)+1.
        // For n <= 65280, umulhi(n, M) == floor(n/d) exactly.
        const unsigned mh = 0xFFFFFFFFu / h + 1u;
        const unsigned mw = 0xFFFFFFFFu / w + 1u;
        const unsigned sr = __umulhi((unsigned)(r - y1) * (unsigned)HCC, mh); // [0,255]
        const float* src = y_cropped + (((long)b * HCC + sr) << 8);
#pragma unroll
        for (int j = 0; j < 4; ++j) {
            const int c = c0 + j;
            float pv = 0.f;
            if (c >= x1 && c < x2) {
                const unsigned sc = __umulhi((unsigned)(c - x1) * (unsigned)WCC, mw); // [0,255]
                pv = src[sc];
            }
            o[j] = pv;
        }
    }

    // ---- retire both 16B stores (independent streams) ----
    *reinterpret_cast<f4*>(out + e) = v;
    *reinterpret_cast<f4*>(out + NELEM + e) = o;
}

extern "C" void kernel_launch(void* const* d_in, const int* in_sizes, int n_in,
                              void* d_out, int out_size, void* d_ws, size_t ws_size,
                              hipStream_t stream) {
    // Inputs (setup_inputs order): x [unused], y_initial, y_cropped, bboxes
    const float* y_initial = (const float*)d_in[1];
    const float* y_cropped = (const float*)d_in[2];
    const int*   bboxes    = (const int*)d_in[3];
    float*       out       = (float*)d_out;

    const int threads = NELEM / 4;            // 2,097,152 threads
    const int block   = 256;
    const int grid    = threads / block;      // 8192 blocks

    TransformedSegmentation_84971632984244_kernel<<<grid, block, 0, stream>>>(
        y_initial, y_cropped, bboxes, out);
}